// Round 24
// baseline (273.766 us; speedup 1.0000x reference)
//
#include <hip/hip_runtime.h>
#include <math.h>

#define B_  2
#define S_  2048
#define D_  1024
#define H_  16
#define HD_ 64
#define BS_ (B_ * S_)          // 4096 token rows
#define SH_ (S_ / 2)           // split-K half length (1024 keys)

typedef float f32x4 __attribute__((ext_vector_type(4)));
typedef int   i32x4 __attribute__((ext_vector_type(4)));

__device__ __forceinline__ float bf2f(unsigned short u) {
    union { unsigned int i; float f; } c; c.i = ((unsigned int)u) << 16; return c.f;
}
__device__ __forceinline__ unsigned short f2bf(float f) {
    union { float f; unsigned int i; } c; c.f = f;
    unsigned int r = c.i + 0x7FFFu + ((c.i >> 16) & 1u);
    return (unsigned short)(r >> 16);
}
__device__ __forceinline__ unsigned int cvtpk_bf16(float lo, float hi) {
    unsigned int r;
    asm volatile("v_cvt_pk_bf16_f32 %0, %1, %2" : "=v"(r) : "v"(lo), "v"(hi));
    return r;
}
__device__ __forceinline__ void gl_lds16(const void* g, void* l) {
    __builtin_amdgcn_global_load_lds((const __attribute__((address_space(1))) void*)g,
                                     (__attribute__((address_space(3))) void*)l, 16, 0, 0);
}
__device__ __forceinline__ void mfma_bf16(f32x4& d, i32x4 a, i32x4 b) {
    asm volatile("v_mfma_f32_16x16x32_bf16 %0, %1, %2, %0" : "+v"(d) : "v"(a), "v"(b));
}

// ---------------------------------------------------------------------------
// Fused prep (single launch, r23-verified): block-range dispatch.
// ---------------------------------------------------------------------------
__device__ __forceinline__ void transpose_tile64(
    const float* __restrict__ W, unsigned short* __restrict__ Wt,
    int K, int N, int bx, int by, float (*t)[65])
{
    const int n0 = bx * 64, k0 = by * 64;
    const int tx = threadIdx.x & 63, ty = threadIdx.x >> 6;   // ty 0..3
#pragma unroll
    for (int kk = 0; kk < 64; kk += 4)
        t[kk + ty][tx] = W[(size_t)(k0 + kk + ty) * N + n0 + tx];
    __syncthreads();
    const int nrow = threadIdx.x >> 2;       // 0..63
    const int kq   = (threadIdx.x & 3) * 4;  // 0,4,8,12
#pragma unroll
    for (int p = 0; p < 4; ++p) {
        const int k = p * 16 + kq;
        ushort4 v = make_ushort4(f2bf(t[k + 0][nrow]), f2bf(t[k + 1][nrow]),
                                 f2bf(t[k + 2][nrow]), f2bf(t[k + 3][nrow]));
        *reinterpret_cast<ushort4*>(Wt + (size_t)(n0 + nrow) * K + k0 + k) = v;
    }
}

__global__ __launch_bounds__(256) void prep_fused(
    const float* __restrict__ x,      unsigned short* __restrict__ xb,
    const float* __restrict__ w_attn, unsigned short* __restrict__ wat,
    const float* __restrict__ w_proj, unsigned short* __restrict__ wpt)
{
    __shared__ float t[64][65];
    const int bid = blockIdx.x;
    if (bid < 2048) {
        const int i = (bid * 256 + threadIdx.x) * 8;
        const float4 a = *reinterpret_cast<const float4*>(x + i);
        const float4 b = *reinterpret_cast<const float4*>(x + i + 4);
        ushort4 u0 = make_ushort4(f2bf(a.x), f2bf(a.y), f2bf(a.z), f2bf(a.w));
        ushort4 u1 = make_ushort4(f2bf(b.x), f2bf(b.y), f2bf(b.z), f2bf(b.w));
        *reinterpret_cast<ushort4*>(xb + i)     = u0;
        *reinterpret_cast<ushort4*>(xb + i + 4) = u1;
    } else if (bid < 2816) {
        const int tb = bid - 2048;                 // 0..767: 48 x 16
        transpose_tile64(w_attn, wat, D_, 3 * D_, tb % 48, tb / 48, t);
    } else {
        const int tb = bid - 2816;                 // 0..255: 16 x 16
        transpose_tile64(w_proj, wpt, D_, D_, tb & 15, tb >> 4, t);
    }
}

// ---------------------------------------------------------------------------
// GEMM: C[M,N] = (A[M,K]_bf16 * Bt[N,K]_bf16^T + bias) * sc(n)   (r8/r12-
// verified core; r21 score-scale fold; r22 XCD-chunked block swizzle).
// Tile choice is STARVATION-dependent (r18).
// ---------------------------------------------------------------------------
template <typename OutT, int BN>
__global__ __launch_bounds__(256) void gemm_bt_bf16(
    const unsigned short* __restrict__ A,   // [M][K]
    const unsigned short* __restrict__ Bt,  // [N][K]
    const float* __restrict__ bias,         // [N]
    OutT* __restrict__ C, int M, int N, int K, int qcols)
{
    constexpr int NW = BN / 2;    // wave n-extent
    constexpr int NI = NW / 16;   // n-frags per wave
    __shared__ alignas(16) unsigned short As[2][4096];
    __shared__ alignas(16) unsigned short Bs[2][BN * 32];

    const int tid  = threadIdx.x;
    const int wave = tid >> 6;
    const int l    = tid & 63;
    const int g    = l >> 4;
    const int r    = l & 15;
    const int wr   = wave >> 1, wc = wave & 1;

    // XCD-chunked swizzle (T1, m157): bijective, nwg % 8 == 0.
    const int nwg  = gridDim.x * gridDim.y;
    const int flat = blockIdx.x + gridDim.x * blockIdx.y;
    const int cpx  = nwg >> 3;
    const int swz  = (flat & 7) * cpx + (flat >> 3);
    const int bx   = swz % gridDim.x;
    const int by   = swz / gridDim.x;

    const int row0 = by * 128;
    const int col0 = bx * BN;
    const float sc = (col0 < qcols) ? 0.125f : 1.0f;   // block-uniform

    const size_t aoff0 = (size_t)(row0 +   0 + l) * K + wave * 8;
    const size_t aoff1 = (size_t)(row0 +  64 + l) * K + wave * 8;
    const size_t boff0 = (size_t)(col0 +   0 + l) * K + wave * 8;
    const size_t boff1 = (size_t)(col0 +  64 + l) * K + wave * 8;  // BN=128 only

    auto stage = [&](int kt, int buf) {
        gl_lds16(A + aoff0 + kt, &As[buf][wave * 1024]);
        gl_lds16(A + aoff1 + kt, &As[buf][wave * 1024 + 512]);
        if constexpr (BN == 128) {
            gl_lds16(Bt + boff0 + kt, &Bs[buf][wave * 1024]);
            gl_lds16(Bt + boff1 + kt, &Bs[buf][wave * 1024 + 512]);
        } else {
            gl_lds16(Bt + boff0 + kt, &Bs[buf][wave * 512]);
        }
    };

    f32x4 acc[4][NI];
#pragma unroll
    for (int mi = 0; mi < 4; ++mi)
#pragma unroll
        for (int ni = 0; ni < NI; ++ni) acc[mi][ni] = (f32x4)0.f;

    stage(0, 0);
    __syncthreads();

    for (int kt = 0; kt < K; kt += 32) {
        const int cur = (kt >> 5) & 1;
        if (kt + 32 < K) stage(kt + 32, cur ^ 1);

        const unsigned short* Ab = &As[cur][g * 1024];
        const unsigned short* Bb = &Bs[cur][g * (BN * 8)];
        i32x4 af[4], bf[NI];
#pragma unroll
        for (int mi = 0; mi < 4; ++mi)
            af[mi] = *reinterpret_cast<const i32x4*>(Ab + (wr * 64 + mi * 16 + r) * 8);
#pragma unroll
        for (int ni = 0; ni < NI; ++ni)
            bf[ni] = *reinterpret_cast<const i32x4*>(Bb + (wc * NW + ni * 16 + r) * 8);
#pragma unroll
        for (int mi = 0; mi < 4; ++mi)
#pragma unroll
            for (int ni = 0; ni < NI; ++ni)
                mfma_bf16(acc[mi][ni], af[mi], bf[ni]);

        __syncthreads();   // drains gl_lds (vmcnt) + ds reads; next buf ready
    }

#pragma unroll
    for (int ni = 0; ni < NI; ++ni) {
        const int n = col0 + wc * NW + ni * 16 + r;
        const float bv = bias[n];
#pragma unroll
        for (int mi = 0; mi < 4; ++mi) {
#pragma unroll
            for (int e = 0; e < 4; ++e) {
                const int m = row0 + wr * 64 + mi * 16 + g * 4 + e;
                const float val = (acc[mi][ni][e] + bv) * sc;
                if constexpr (sizeof(OutT) == 2)
                    C[(size_t)m * N + n] = (OutT)f2bf(val);
                else
                    C[(size_t)m * N + n] = (OutT)val;
            }
        }
    }
}

// ---------------------------------------------------------------------------
// Split-K MFMA flash attention, pass 1. r13/r21/r22-verified body; keys
// split in half across blockIdx.z = b*2+half -> grid 1024 = 4 blocks/CU.
// __launch_bounds__(512, 8) pins VGPR <= 64 (m69 halving boundary) so the
// doubled grid actually doubles occupancy — r11's null was run AT the 64
// boundary and couldn't benefit. Partials are normalized bf16 + (m,l) f32.
// ---------------------------------------------------------------------------
__global__ __launch_bounds__(512, 8) void flash_attn_split(
    const unsigned short* __restrict__ qkv,  // [BS][3072], Q cols pre-scaled
    const float* __restrict__ mask,          // [B][S]
    unsigned short* __restrict__ op0,        // [BS][1024] partial half 0
    unsigned short* __restrict__ op1,        // [BS][1024] partial half 1
    float2* __restrict__ ml)                 // [2][B][H][S] (m, l)
{
    __shared__ alignas(16) unsigned short Klds[2][4096];  // [key][d^((key&7)<<3)]
    __shared__ alignas(16) unsigned short Vt[2][4096];    // [d][key^((d&7)<<3)]

    const int tid  = threadIdx.x;
    const int wave = tid >> 6;          // 0..7
    const int l    = tid & 63;
    const int g    = l >> 4;
    const int r    = l & 15;

    // XCD-chunked swizzle: 1024 blocks, chunk = 128 per XCD = 8 heads of one
    // (b,half) -> K/V footprint 2 MB per L2. Bijective.
    const int flat = blockIdx.x + 16 * blockIdx.y + 256 * blockIdx.z;
    const int swz  = (flat & 7) * 128 + (flat >> 3);
    const int zz   = swz >> 8;          // 0..3 = b*2 + half
    const int b    = zz >> 1;
    const int half = zz & 1;
    const int kv0  = half * SH_;
    const int h    = (swz >> 4) & 15;
    const int q0   = (swz & 15) * 128;
    const int qw   = q0 + wave * 16;    // this wave's 16 q-rows

    const size_t rs = 3 * (size_t)D_;
    const unsigned short* qb = qkv + (size_t)b * S_ * rs + (size_t)h * HD_;
    const unsigned short* kb = qb + D_;
    const unsigned short* vb = qb + 2 * D_;
    const float* mrow = mask + (size_t)b * S_;

    // Q fragments: q = qw + r, d = ks*32 + g*8 + j
    i32x4 qf[2];
#pragma unroll
    for (int ks = 0; ks < 2; ++ks)
        qf[ks] = *reinterpret_cast<const i32x4*>(
            qb + (size_t)(qw + r) * rs + ks * 32 + g * 8);

    // K staging (waves 0-3, r4 mapping): keys kt + wave*16 + t*8 + (l>>3)
    const int kkey = (wave & 3) * 16 + (l >> 3);
    const int kuni = ((l & 7) ^ (l >> 3)) * 8;
    // V staging (waves 4-7, r4 mapping with w' = wave-4)
    const int vkey = (wave & 3) * 16 + (l >> 2);
    const int vpart = l & 3;

    ushort4 vr[4];   // in-flight V registers (next tile's data)
    auto vload = [&](int kt) {
#pragma unroll
        for (int p = 0; p < 4; ++p)
            vr[p] = *reinterpret_cast<const ushort4*>(
                vb + (size_t)(kt + vkey) * rs + p * 16 + vpart * 4);
    };
    auto vwrite = [&](int buf) {
#pragma unroll
        for (int p = 0; p < 4; ++p) {
            const int d0 = p * 16 + vpart * 4;
            Vt[buf][(d0 + 0) * 64 + (vkey ^ (((d0 + 0) & 7) << 3))] = vr[p].x;
            Vt[buf][(d0 + 1) * 64 + (vkey ^ (((d0 + 1) & 7) << 3))] = vr[p].y;
            Vt[buf][(d0 + 2) * 64 + (vkey ^ (((d0 + 2) & 7) << 3))] = vr[p].z;
            Vt[buf][(d0 + 3) * 64 + (vkey ^ (((d0 + 3) & 7) << 3))] = vr[p].w;
        }
    };

    f32x4 acc[4];     // O^T: d = mi*16 + g*4 + e, q = r
    float m_i = -1e30f, l_i = 0.f;
#pragma unroll
    for (int mi = 0; mi < 4; ++mi) acc[mi] = (f32x4)0.f;

    // prologue: tile kv0 into buf 0; V regs for tile kv0+64 in flight
    if (wave < 4) {
        gl_lds16(kb + (size_t)(kv0 + kkey) * rs + kuni,     &Klds[0][(wave & 3) * 1024]);
        gl_lds16(kb + (size_t)(kv0 + kkey + 8) * rs + kuni, &Klds[0][(wave & 3) * 1024 + 512]);
    } else {
        vload(kv0);
        vwrite(0);        // waits vmcnt internally (prologue only)
        vload(kv0 + 64);  // next tile regs, drains at first barrier
    }
    __syncthreads();

    for (int kt = kv0; kt < kv0 + SH_; kt += 64) {
        const int cur = ((kt - kv0) >> 6) & 1;
        if (wave < 4) {
            if (kt + 64 < kv0 + SH_) {
                gl_lds16(kb + (size_t)(kt + 64 + kkey) * rs + kuni,
                         &Klds[cur ^ 1][(wave & 3) * 1024]);
                gl_lds16(kb + (size_t)(kt + 64 + kkey + 8) * rs + kuni,
                         &Klds[cur ^ 1][(wave & 3) * 1024 + 512]);
            }
        } else {
            if (kt + 64 < kv0 + SH_) vwrite(cur ^ 1);   // tile t+1 (drained)
            if (kt + 128 < kv0 + SH_) vload(kt + 128);  // issue t+2
        }

        const unsigned short* Kb = Klds[cur];
        const unsigned short* Vb = Vt[cur];

        // --- S^T = (Q/8)·K^T + mask : C-in = mask (key = S^T row) ---
        f32x4 s[4];
#pragma unroll
        for (int mi = 0; mi < 4; ++mi) {
            const float4 mk = *reinterpret_cast<const float4*>(
                mrow + kt + mi * 16 + g * 4);
            s[mi][0] = mk.x; s[mi][1] = mk.y; s[mi][2] = mk.z; s[mi][3] = mk.w;
        }
#pragma unroll
        for (int ks = 0; ks < 2; ++ks)
#pragma unroll
            for (int mi = 0; mi < 4; ++mi) {
                const i32x4 kf = *reinterpret_cast<const i32x4*>(
                    Kb + (mi * 16 + r) * 64 + ((ks * 32 + g * 8) ^ ((r & 7) << 3)));
                mfma_bf16(s[mi], kf, qf[ks]);
            }

        // --- online softmax + pack P to bf16 ---
        float tmax = -1e30f;
#pragma unroll
        for (int mi = 0; mi < 4; ++mi)
#pragma unroll
            for (int e = 0; e < 4; ++e)
                tmax = fmaxf(tmax, s[mi][e]);
        tmax = fmaxf(tmax, __shfl_xor(tmax, 16));
        tmax = fmaxf(tmax, __shfl_xor(tmax, 32));
        const float mnew = fmaxf(m_i, tmax);
        const float corr = __expf(m_i - mnew);
        m_i = mnew;

        unsigned int pk[4][2];   // [mi][wl]: keys (mi*16 + g*4 + 2wl, +1)
        float ls = 0.f;
#pragma unroll
        for (int mi = 0; mi < 4; ++mi) {
            const float p0 = __expf(s[mi][0] - mnew);
            const float p1 = __expf(s[mi][1] - mnew);
            const float p2 = __expf(s[mi][2] - mnew);
            const float p3 = __expf(s[mi][3] - mnew);
            ls += (p0 + p1) + (p2 + p3);
            pk[mi][0] = cvtpk_bf16(p0, p1);
            pk[mi][1] = cvtpk_bf16(p2, p3);
        }
        l_i = l_i * corr + ls;   // lane-partial over g; reduced at end
#pragma unroll
        for (int mi = 0; mi < 4; ++mi) acc[mi] *= corr;

        // --- PV: O^T += V^T · P^T ---
#pragma unroll
        for (int ks = 0; ks < 2; ++ks) {
            i32x4 pf;   // word w = keys ks*32 + g*8 + 2w, +1 of q-row r
#pragma unroll
            for (int w = 0; w < 4; ++w) {
                const int src = (((g & 1) * 2 + (w >> 1)) << 4) + r;
                const unsigned int vA = __shfl(pk[2 * ks + 0][w & 1], src);
                const unsigned int vB = __shfl(pk[2 * ks + 1][w & 1], src);
                pf[w] = (int)((g >> 1) ? vB : vA);
            }
#pragma unroll
            for (int mi = 0; mi < 4; ++mi) {
                const i32x4 vf = *reinterpret_cast<const i32x4*>(
                    Vb + (mi * 16 + r) * 64 + ((ks * 32 + g * 8) ^ ((r & 7) << 3)));
                mfma_bf16(acc[mi], vf, pf);
            }
        }

        __syncthreads();   // drains stage's vmcnt/lgkm; next buf ready
    }

    // --- epilogue: reduce l over g-lanes, write normalized partial + (m,l) ---
    float lf = l_i;
    lf += __shfl_xor(lf, 16);
    lf += __shfl_xor(lf, 32);
    const float inv = 1.0f / lf;
    const size_t token = (size_t)b * S_ + qw + r;
    unsigned short* obase = half ? op1 : op0;
#pragma unroll
    for (int mi = 0; mi < 4; ++mi) {
        const f32x4 v = acc[mi] * inv;
        uint2 w;
        w.x = cvtpk_bf16(v[0], v[1]);
        w.y = cvtpk_bf16(v[2], v[3]);
        *reinterpret_cast<uint2*>(
            obase + token * D_ + h * HD_ + mi * 16 + g * 4) = w;
    }
    if (l < 16) {   // g==0 lane per q-row
        const size_t mli = (((size_t)half * B_ + b) * H_ + h) * S_ + qw + l;
        ml[mli] = make_float2(m_i, lf);
    }
}

// ---------------------------------------------------------------------------
// Split-K combine (r11-verified): out = (w0*O0 + w1*O1)/(w0+w1),
// w_h = l_h * exp(m_h - M). In-place on o0.
// ---------------------------------------------------------------------------
__global__ __launch_bounds__(256) void combine_halves(
    unsigned short* o0,                       // [BS][1024] in/out (half 0)
    const unsigned short* __restrict__ o1,    // [BS][1024] (half 1)
    const float2* __restrict__ ml)            // [2][B][H][S]
{
    const int gid   = blockIdx.x * 256 + threadIdx.x;   // 0 .. 524287
    const int chunk = gid & 127;                         // 8-elem chunk in row
    const int token = gid >> 7;                          // 0..4095
    const int h     = chunk >> 3;
    const int b     = token >> 11;
    const int q     = token & 2047;

    const size_t mli = (((size_t)b) * H_ + h) * S_ + q;
    const float2 a0 = ml[mli];
    const float2 a1 = ml[(size_t)B_ * H_ * S_ + mli];
    const float M  = fmaxf(a0.x, a1.x);
    float w0 = a0.y * __expf(a0.x - M);
    float w1 = a1.y * __expf(a1.x - M);
    const float inv = 1.0f / (w0 + w1);
    w0 *= inv; w1 *= inv;

    const size_t off = (size_t)token * D_ + chunk * 8;
    const ushort4 x0 = *reinterpret_cast<const ushort4*>(o0 + off);
    const ushort4 x1 = *reinterpret_cast<const ushort4*>(o0 + off + 4);
    const ushort4 y0 = *reinterpret_cast<const ushort4*>(o1 + off);
    const ushort4 y1 = *reinterpret_cast<const ushort4*>(o1 + off + 4);
    ushort4 r0, r1;
    r0.x = f2bf(w0 * bf2f(x0.x) + w1 * bf2f(y0.x));
    r0.y = f2bf(w0 * bf2f(x0.y) + w1 * bf2f(y0.y));
    r0.z = f2bf(w0 * bf2f(x0.z) + w1 * bf2f(y0.z));
    r0.w = f2bf(w0 * bf2f(x0.w) + w1 * bf2f(y0.w));
    r1.x = f2bf(w0 * bf2f(x1.x) + w1 * bf2f(y1.x));
    r1.y = f2bf(w0 * bf2f(x1.y) + w1 * bf2f(y1.y));
    r1.z = f2bf(w0 * bf2f(x1.z) + w1 * bf2f(y1.z));
    r1.w = f2bf(w0 * bf2f(x1.w) + w1 * bf2f(y1.w));
    *reinterpret_cast<ushort4*>(o0 + off)     = r0;
    *reinterpret_cast<ushort4*>(o0 + off + 4) = r1;
}

// ---------------------------------------------------------------------------
extern "C" void kernel_launch(void* const* d_in, const int* in_sizes, int n_in,
                              void* d_out, int out_size, void* d_ws, size_t ws_size,
                              hipStream_t stream)
{
    const float* x      = (const float*)d_in[0];   // [2,2048,1024]
    const float* amask  = (const float*)d_in[1];   // [2,2048]
    const float* w_attn = (const float*)d_in[2];   // [1024,3072]
    const float* b_attn = (const float*)d_in[3];   // [3072]
    const float* w_proj = (const float*)d_in[4];   // [1024,1024]
    const float* b_proj = (const float*)d_in[5];   // [1024]
    float* out = (float*)d_out;                    // [2,2048,1024] fp32

    unsigned short* qkvb  = (unsigned short*)d_ws;                  // [4096][3072] bf16
    unsigned short* attnb = qkvb  + (size_t)BS_ * 3 * D_;           // partial 0 / final
    unsigned short* xb    = attnb + (size_t)BS_ * D_;               // x, then partial 1
    unsigned short* wat   = xb    + (size_t)BS_ * D_;               // w_attn^T, then ml
    unsigned short* wpt   = wat   + (size_t)3 * D_ * D_;            // [1024][1024] bf16
    float2*         mlbuf = (float2*)wat;                           // 1 MB, overlays wat

    // 0) fused prep: x->bf16 + both weight transposes, one launch
    prep_fused<<<3072, 256, 0, stream>>>(x, xb, w_attn, wat, w_proj, wpt);

    // 1) QKV projection (bf16 MFMA, BN=128, XCD-swizzled) -> bf16 qkv
    //    Q columns (n < 1024) pre-scaled by 1/8 (exact in bf16).
    gemm_bt_bf16<unsigned short, 128><<<dim3(3 * D_ / 128, BS_ / 128), 256, 0, stream>>>(
        xb, wat, b_attn, qkvb, BS_, 3 * D_, D_, D_);

    // 2) split-K flash pass 1 (grid 1024 = 4 blocks/CU at VGPR<=64)
    flash_attn_split<<<dim3(S_ / 128, H_, B_ * 2), 512, 0, stream>>>(
        qkvb, amask, attnb, xb, mlbuf);

    // 3) combine halves in-place into attnb
    combine_halves<<<(BS_ * D_ / 8) / 256, 256, 0, stream>>>(attnb, xb, mlbuf);

    // 4) output projection (bf16 MFMA, BN=64, XCD-swizzled) -> fp32
    gemm_bt_bf16<float, 64><<<dim3(D_ / 64, BS_ / 128), 256, 0, stream>>>(
        attnb, wpt, b_proj, out, BS_, D_, D_, 0);
}

// Round 25
// 273.485 us; speedup vs baseline: 1.0010x; 1.0010x over previous
//
#include <hip/hip_runtime.h>
#include <math.h>

#define B_  2
#define S_  2048
#define D_  1024
#define H_  16
#define HD_ 64
#define BS_ (B_ * S_)          // 4096 token rows
#define SH_ (S_ / 2)           // split-K half length (1024 keys)

typedef float f32x4 __attribute__((ext_vector_type(4)));
typedef int   i32x4 __attribute__((ext_vector_type(4)));

__device__ __forceinline__ float bf2f(unsigned short u) {
    union { unsigned int i; float f; } c; c.i = ((unsigned int)u) << 16; return c.f;
}
__device__ __forceinline__ unsigned short f2bf(float f) {
    union { float f; unsigned int i; } c; c.f = f;
    unsigned int r = c.i + 0x7FFFu + ((c.i >> 16) & 1u);
    return (unsigned short)(r >> 16);
}
__device__ __forceinline__ unsigned int cvtpk_bf16(float lo, float hi) {
    unsigned int r;
    asm volatile("v_cvt_pk_bf16_f32 %0, %1, %2" : "=v"(r) : "v"(lo), "v"(hi));
    return r;
}
__device__ __forceinline__ void gl_lds16(const void* g, void* l) {
    __builtin_amdgcn_global_load_lds((const __attribute__((address_space(1))) void*)g,
                                     (__attribute__((address_space(3))) void*)l, 16, 0, 0);
}
__device__ __forceinline__ void mfma_bf16(f32x4& d, i32x4 a, i32x4 b) {
    asm volatile("v_mfma_f32_16x16x32_bf16 %0, %1, %2, %0" : "+v"(d) : "v"(a), "v"(b));
}

// ---------------------------------------------------------------------------
// Fused prep (single launch, r23-verified): block-range dispatch.
// ---------------------------------------------------------------------------
__device__ __forceinline__ void transpose_tile64(
    const float* __restrict__ W, unsigned short* __restrict__ Wt,
    int K, int N, int bx, int by, float (*t)[65])
{
    const int n0 = bx * 64, k0 = by * 64;
    const int tx = threadIdx.x & 63, ty = threadIdx.x >> 6;   // ty 0..3
#pragma unroll
    for (int kk = 0; kk < 64; kk += 4)
        t[kk + ty][tx] = W[(size_t)(k0 + kk + ty) * N + n0 + tx];
    __syncthreads();
    const int nrow = threadIdx.x >> 2;       // 0..63
    const int kq   = (threadIdx.x & 3) * 4;  // 0,4,8,12
#pragma unroll
    for (int p = 0; p < 4; ++p) {
        const int k = p * 16 + kq;
        ushort4 v = make_ushort4(f2bf(t[k + 0][nrow]), f2bf(t[k + 1][nrow]),
                                 f2bf(t[k + 2][nrow]), f2bf(t[k + 3][nrow]));
        *reinterpret_cast<ushort4*>(Wt + (size_t)(n0 + nrow) * K + k0 + k) = v;
    }
}

__global__ __launch_bounds__(256) void prep_fused(
    const float* __restrict__ x,      unsigned short* __restrict__ xb,
    const float* __restrict__ w_attn, unsigned short* __restrict__ wat,
    const float* __restrict__ w_proj, unsigned short* __restrict__ wpt)
{
    __shared__ float t[64][65];
    const int bid = blockIdx.x;
    if (bid < 2048) {
        const int i = (bid * 256 + threadIdx.x) * 8;
        const float4 a = *reinterpret_cast<const float4*>(x + i);
        const float4 b = *reinterpret_cast<const float4*>(x + i + 4);
        ushort4 u0 = make_ushort4(f2bf(a.x), f2bf(a.y), f2bf(a.z), f2bf(a.w));
        ushort4 u1 = make_ushort4(f2bf(b.x), f2bf(b.y), f2bf(b.z), f2bf(b.w));
        *reinterpret_cast<ushort4*>(xb + i)     = u0;
        *reinterpret_cast<ushort4*>(xb + i + 4) = u1;
    } else if (bid < 2816) {
        const int tb = bid - 2048;                 // 0..767: 48 x 16
        transpose_tile64(w_attn, wat, D_, 3 * D_, tb % 48, tb / 48, t);
    } else {
        const int tb = bid - 2816;                 // 0..255: 16 x 16
        transpose_tile64(w_proj, wpt, D_, D_, tb & 15, tb >> 4, t);
    }
}

// ---------------------------------------------------------------------------
// GEMM: C[M,N] = (A[M,K]_bf16 * Bt[N,K]_bf16^T + bias) * sc(n)   (r8/r12-
// verified core; r21 score-scale fold; r22 XCD-chunked block swizzle).
// Tile choice is STARVATION-dependent (r18).
// ---------------------------------------------------------------------------
template <typename OutT, int BN>
__global__ __launch_bounds__(256) void gemm_bt_bf16(
    const unsigned short* __restrict__ A,   // [M][K]
    const unsigned short* __restrict__ Bt,  // [N][K]
    const float* __restrict__ bias,         // [N]
    OutT* __restrict__ C, int M, int N, int K, int qcols)
{
    constexpr int NW = BN / 2;    // wave n-extent
    constexpr int NI = NW / 16;   // n-frags per wave
    __shared__ alignas(16) unsigned short As[2][4096];
    __shared__ alignas(16) unsigned short Bs[2][BN * 32];

    const int tid  = threadIdx.x;
    const int wave = tid >> 6;
    const int l    = tid & 63;
    const int g    = l >> 4;
    const int r    = l & 15;
    const int wr   = wave >> 1, wc = wave & 1;

    // XCD-chunked swizzle (T1, m157): bijective, nwg % 8 == 0.
    const int nwg  = gridDim.x * gridDim.y;
    const int flat = blockIdx.x + gridDim.x * blockIdx.y;
    const int cpx  = nwg >> 3;
    const int swz  = (flat & 7) * cpx + (flat >> 3);
    const int bx   = swz % gridDim.x;
    const int by   = swz / gridDim.x;

    const int row0 = by * 128;
    const int col0 = bx * BN;
    const float sc = (col0 < qcols) ? 0.125f : 1.0f;   // block-uniform

    const size_t aoff0 = (size_t)(row0 +   0 + l) * K + wave * 8;
    const size_t aoff1 = (size_t)(row0 +  64 + l) * K + wave * 8;
    const size_t boff0 = (size_t)(col0 +   0 + l) * K + wave * 8;
    const size_t boff1 = (size_t)(col0 +  64 + l) * K + wave * 8;  // BN=128 only

    auto stage = [&](int kt, int buf) {
        gl_lds16(A + aoff0 + kt, &As[buf][wave * 1024]);
        gl_lds16(A + aoff1 + kt, &As[buf][wave * 1024 + 512]);
        if constexpr (BN == 128) {
            gl_lds16(Bt + boff0 + kt, &Bs[buf][wave * 1024]);
            gl_lds16(Bt + boff1 + kt, &Bs[buf][wave * 1024 + 512]);
        } else {
            gl_lds16(Bt + boff0 + kt, &Bs[buf][wave * 512]);
        }
    };

    f32x4 acc[4][NI];
#pragma unroll
    for (int mi = 0; mi < 4; ++mi)
#pragma unroll
        for (int ni = 0; ni < NI; ++ni) acc[mi][ni] = (f32x4)0.f;

    stage(0, 0);
    __syncthreads();

    for (int kt = 0; kt < K; kt += 32) {
        const int cur = (kt >> 5) & 1;
        if (kt + 32 < K) stage(kt + 32, cur ^ 1);

        const unsigned short* Ab = &As[cur][g * 1024];
        const unsigned short* Bb = &Bs[cur][g * (BN * 8)];
        i32x4 af[4], bf[NI];
#pragma unroll
        for (int mi = 0; mi < 4; ++mi)
            af[mi] = *reinterpret_cast<const i32x4*>(Ab + (wr * 64 + mi * 16 + r) * 8);
#pragma unroll
        for (int ni = 0; ni < NI; ++ni)
            bf[ni] = *reinterpret_cast<const i32x4*>(Bb + (wc * NW + ni * 16 + r) * 8);
#pragma unroll
        for (int mi = 0; mi < 4; ++mi)
#pragma unroll
            for (int ni = 0; ni < NI; ++ni)
                mfma_bf16(acc[mi][ni], af[mi], bf[ni]);

        __syncthreads();   // drains gl_lds (vmcnt) + ds reads; next buf ready
    }

#pragma unroll
    for (int ni = 0; ni < NI; ++ni) {
        const int n = col0 + wc * NW + ni * 16 + r;
        const float bv = bias[n];
#pragma unroll
        for (int mi = 0; mi < 4; ++mi) {
#pragma unroll
            for (int e = 0; e < 4; ++e) {
                const int m = row0 + wr * 64 + mi * 16 + g * 4 + e;
                const float val = (acc[mi][ni][e] + bv) * sc;
                if constexpr (sizeof(OutT) == 2)
                    C[(size_t)m * N + n] = (OutT)f2bf(val);
                else
                    C[(size_t)m * N + n] = (OutT)val;
            }
        }
    }
}

// ---------------------------------------------------------------------------
// Split-K MFMA flash attention, pass 1. r13/r21/r22-verified body; keys
// split in half across blockIdx.z = b*2+half -> grid 1024 = 4 blocks/CU.
// __launch_bounds__(512, 8) pins VGPR <= 64 (m69 halving boundary) so the
// doubled grid actually doubles occupancy — r11's null was run AT the 64
// boundary and couldn't benefit. Partials are normalized bf16 + (m,l) f32.
// ---------------------------------------------------------------------------
__global__ __launch_bounds__(512, 8) void flash_attn_split(
    const unsigned short* __restrict__ qkv,  // [BS][3072], Q cols pre-scaled
    const float* __restrict__ mask,          // [B][S]
    unsigned short* __restrict__ op0,        // [BS][1024] partial half 0
    unsigned short* __restrict__ op1,        // [BS][1024] partial half 1
    float2* __restrict__ ml)                 // [2][B][H][S] (m, l)
{
    __shared__ alignas(16) unsigned short Klds[2][4096];  // [key][d^((key&7)<<3)]
    __shared__ alignas(16) unsigned short Vt[2][4096];    // [d][key^((d&7)<<3)]

    const int tid  = threadIdx.x;
    const int wave = tid >> 6;          // 0..7
    const int l    = tid & 63;
    const int g    = l >> 4;
    const int r    = l & 15;

    // XCD-chunked swizzle: 1024 blocks, chunk = 128 per XCD = 8 heads of one
    // (b,half) -> K/V footprint 2 MB per L2. Bijective.
    const int flat = blockIdx.x + 16 * blockIdx.y + 256 * blockIdx.z;
    const int swz  = (flat & 7) * 128 + (flat >> 3);
    const int zz   = swz >> 8;          // 0..3 = b*2 + half
    const int b    = zz >> 1;
    const int half = zz & 1;
    const int kv0  = half * SH_;
    const int h    = (swz >> 4) & 15;
    const int q0   = (swz & 15) * 128;
    const int qw   = q0 + wave * 16;    // this wave's 16 q-rows

    const size_t rs = 3 * (size_t)D_;
    const unsigned short* qb = qkv + (size_t)b * S_ * rs + (size_t)h * HD_;
    const unsigned short* kb = qb + D_;
    const unsigned short* vb = qb + 2 * D_;
    const float* mrow = mask + (size_t)b * S_;

    // Q fragments: q = qw + r, d = ks*32 + g*8 + j
    i32x4 qf[2];
#pragma unroll
    for (int ks = 0; ks < 2; ++ks)
        qf[ks] = *reinterpret_cast<const i32x4*>(
            qb + (size_t)(qw + r) * rs + ks * 32 + g * 8);

    // K staging (waves 0-3, r4 mapping): keys kt + wave*16 + t*8 + (l>>3)
    const int kkey = (wave & 3) * 16 + (l >> 3);
    const int kuni = ((l & 7) ^ (l >> 3)) * 8;
    // V staging (waves 4-7, r4 mapping with w' = wave-4)
    const int vkey = (wave & 3) * 16 + (l >> 2);
    const int vpart = l & 3;

    ushort4 vr[4];   // in-flight V registers (next tile's data)
    auto vload = [&](int kt) {
#pragma unroll
        for (int p = 0; p < 4; ++p)
            vr[p] = *reinterpret_cast<const ushort4*>(
                vb + (size_t)(kt + vkey) * rs + p * 16 + vpart * 4);
    };
    auto vwrite = [&](int buf) {
#pragma unroll
        for (int p = 0; p < 4; ++p) {
            const int d0 = p * 16 + vpart * 4;
            Vt[buf][(d0 + 0) * 64 + (vkey ^ (((d0 + 0) & 7) << 3))] = vr[p].x;
            Vt[buf][(d0 + 1) * 64 + (vkey ^ (((d0 + 1) & 7) << 3))] = vr[p].y;
            Vt[buf][(d0 + 2) * 64 + (vkey ^ (((d0 + 2) & 7) << 3))] = vr[p].z;
            Vt[buf][(d0 + 3) * 64 + (vkey ^ (((d0 + 3) & 7) << 3))] = vr[p].w;
        }
    };

    f32x4 acc[4];     // O^T: d = mi*16 + g*4 + e, q = r
    float m_i = -1e30f, l_i = 0.f;
#pragma unroll
    for (int mi = 0; mi < 4; ++mi) acc[mi] = (f32x4)0.f;

    // prologue: tile kv0 into buf 0; V regs for tile kv0+64 in flight
    if (wave < 4) {
        gl_lds16(kb + (size_t)(kv0 + kkey) * rs + kuni,     &Klds[0][(wave & 3) * 1024]);
        gl_lds16(kb + (size_t)(kv0 + kkey + 8) * rs + kuni, &Klds[0][(wave & 3) * 1024 + 512]);
    } else {
        vload(kv0);
        vwrite(0);        // waits vmcnt internally (prologue only)
        vload(kv0 + 64);  // next tile regs, drains at first barrier
    }
    __syncthreads();

    for (int kt = kv0; kt < kv0 + SH_; kt += 64) {
        const int cur = ((kt - kv0) >> 6) & 1;
        if (wave < 4) {
            if (kt + 64 < kv0 + SH_) {
                gl_lds16(kb + (size_t)(kt + 64 + kkey) * rs + kuni,
                         &Klds[cur ^ 1][(wave & 3) * 1024]);
                gl_lds16(kb + (size_t)(kt + 64 + kkey + 8) * rs + kuni,
                         &Klds[cur ^ 1][(wave & 3) * 1024 + 512]);
            }
        } else {
            if (kt + 64 < kv0 + SH_) vwrite(cur ^ 1);   // tile t+1 (drained)
            if (kt + 128 < kv0 + SH_) vload(kt + 128);  // issue t+2
        }

        const unsigned short* Kb = Klds[cur];
        const unsigned short* Vb = Vt[cur];

        // --- S^T = (Q/8)·K^T + mask : C-in = mask (key = S^T row) ---
        f32x4 s[4];
#pragma unroll
        for (int mi = 0; mi < 4; ++mi) {
            const float4 mk = *reinterpret_cast<const float4*>(
                mrow + kt + mi * 16 + g * 4);
            s[mi][0] = mk.x; s[mi][1] = mk.y; s[mi][2] = mk.z; s[mi][3] = mk.w;
        }
#pragma unroll
        for (int ks = 0; ks < 2; ++ks)
#pragma unroll
            for (int mi = 0; mi < 4; ++mi) {
                const i32x4 kf = *reinterpret_cast<const i32x4*>(
                    Kb + (mi * 16 + r) * 64 + ((ks * 32 + g * 8) ^ ((r & 7) << 3)));
                mfma_bf16(s[mi], kf, qf[ks]);
            }

        // --- online softmax + pack P to bf16 ---
        float tmax = -1e30f;
#pragma unroll
        for (int mi = 0; mi < 4; ++mi)
#pragma unroll
            for (int e = 0; e < 4; ++e)
                tmax = fmaxf(tmax, s[mi][e]);
        tmax = fmaxf(tmax, __shfl_xor(tmax, 16));
        tmax = fmaxf(tmax, __shfl_xor(tmax, 32));
        const float mnew = fmaxf(m_i, tmax);
        const float corr = __expf(m_i - mnew);
        m_i = mnew;

        unsigned int pk[4][2];   // [mi][wl]: keys (mi*16 + g*4 + 2wl, +1)
        float ls = 0.f;
#pragma unroll
        for (int mi = 0; mi < 4; ++mi) {
            const float p0 = __expf(s[mi][0] - mnew);
            const float p1 = __expf(s[mi][1] - mnew);
            const float p2 = __expf(s[mi][2] - mnew);
            const float p3 = __expf(s[mi][3] - mnew);
            ls += (p0 + p1) + (p2 + p3);
            pk[mi][0] = cvtpk_bf16(p0, p1);
            pk[mi][1] = cvtpk_bf16(p2, p3);
        }
        l_i = l_i * corr + ls;   // lane-partial over g; reduced at end
#pragma unroll
        for (int mi = 0; mi < 4; ++mi) acc[mi] *= corr;

        // --- PV: O^T += V^T · P^T ---
#pragma unroll
        for (int ks = 0; ks < 2; ++ks) {
            i32x4 pf;   // word w = keys ks*32 + g*8 + 2w, +1 of q-row r
#pragma unroll
            for (int w = 0; w < 4; ++w) {
                const int src = (((g & 1) * 2 + (w >> 1)) << 4) + r;
                const unsigned int vA = __shfl(pk[2 * ks + 0][w & 1], src);
                const unsigned int vB = __shfl(pk[2 * ks + 1][w & 1], src);
                pf[w] = (int)((g >> 1) ? vB : vA);
            }
#pragma unroll
            for (int mi = 0; mi < 4; ++mi) {
                const i32x4 vf = *reinterpret_cast<const i32x4*>(
                    Vb + (mi * 16 + r) * 64 + ((ks * 32 + g * 8) ^ ((r & 7) << 3)));
                mfma_bf16(acc[mi], vf, pf);
            }
        }

        __syncthreads();   // drains stage's vmcnt/lgkm; next buf ready
    }

    // --- epilogue: reduce l over g-lanes, write normalized partial + (m,l) ---
    float lf = l_i;
    lf += __shfl_xor(lf, 16);
    lf += __shfl_xor(lf, 32);
    const float inv = 1.0f / lf;
    const size_t token = (size_t)b * S_ + qw + r;
    unsigned short* obase = half ? op1 : op0;
#pragma unroll
    for (int mi = 0; mi < 4; ++mi) {
        const f32x4 v = acc[mi] * inv;
        uint2 w;
        w.x = cvtpk_bf16(v[0], v[1]);
        w.y = cvtpk_bf16(v[2], v[3]);
        *reinterpret_cast<uint2*>(
            obase + token * D_ + h * HD_ + mi * 16 + g * 4) = w;
    }
    if (l < 16) {   // g==0 lane per q-row
        const size_t mli = (((size_t)half * B_ + b) * H_ + h) * S_ + qw + l;
        ml[mli] = make_float2(m_i, lf);
    }
}

// ---------------------------------------------------------------------------
// Split-K combine (r11-verified): out = (w0*O0 + w1*O1)/(w0+w1),
// w_h = l_h * exp(m_h - M). In-place on o0.
// ---------------------------------------------------------------------------
__global__ __launch_bounds__(256) void combine_halves(
    unsigned short* o0,                       // [BS][1024] in/out (half 0)
    const unsigned short* __restrict__ o1,    // [BS][1024] (half 1)
    const float2* __restrict__ ml)            // [2][B][H][S]
{
    const int gid   = blockIdx.x * 256 + threadIdx.x;   // 0 .. 524287
    const int chunk = gid & 127;                         // 8-elem chunk in row
    const int token = gid >> 7;                          // 0..4095
    const int h     = chunk >> 3;
    const int b     = token >> 11;
    const int q     = token & 2047;

    const size_t mli = (((size_t)b) * H_ + h) * S_ + q;
    const float2 a0 = ml[mli];
    const float2 a1 = ml[(size_t)B_ * H_ * S_ + mli];
    const float M  = fmaxf(a0.x, a1.x);
    float w0 = a0.y * __expf(a0.x - M);
    float w1 = a1.y * __expf(a1.x - M);
    const float inv = 1.0f / (w0 + w1);
    w0 *= inv; w1 *= inv;

    const size_t off = (size_t)token * D_ + chunk * 8;
    const ushort4 x0 = *reinterpret_cast<const ushort4*>(o0 + off);
    const ushort4 x1 = *reinterpret_cast<const ushort4*>(o0 + off + 4);
    const ushort4 y0 = *reinterpret_cast<const ushort4*>(o1 + off);
    const ushort4 y1 = *reinterpret_cast<const ushort4*>(o1 + off + 4);
    ushort4 r0, r1;
    r0.x = f2bf(w0 * bf2f(x0.x) + w1 * bf2f(y0.x));
    r0.y = f2bf(w0 * bf2f(x0.y) + w1 * bf2f(y0.y));
    r0.z = f2bf(w0 * bf2f(x0.z) + w1 * bf2f(y0.z));
    r0.w = f2bf(w0 * bf2f(x0.w) + w1 * bf2f(y0.w));
    r1.x = f2bf(w0 * bf2f(x1.x) + w1 * bf2f(y1.x));
    r1.y = f2bf(w0 * bf2f(x1.y) + w1 * bf2f(y1.y));
    r1.z = f2bf(w0 * bf2f(x1.z) + w1 * bf2f(y1.z));
    r1.w = f2bf(w0 * bf2f(x1.w) + w1 * bf2f(y1.w));
    *reinterpret_cast<ushort4*>(o0 + off)     = r0;
    *reinterpret_cast<ushort4*>(o0 + off + 4) = r1;
}

// ---------------------------------------------------------------------------
extern "C" void kernel_launch(void* const* d_in, const int* in_sizes, int n_in,
                              void* d_out, int out_size, void* d_ws, size_t ws_size,
                              hipStream_t stream)
{
    const float* x      = (const float*)d_in[0];   // [2,2048,1024]
    const float* amask  = (const float*)d_in[1];   // [2,2048]
    const float* w_attn = (const float*)d_in[2];   // [1024,3072]
    const float* b_attn = (const float*)d_in[3];   // [3072]
    const float* w_proj = (const float*)d_in[4];   // [1024,1024]
    const float* b_proj = (const float*)d_in[5];   // [1024]
    float* out = (float*)d_out;                    // [2,2048,1024] fp32

    unsigned short* qkvb  = (unsigned short*)d_ws;                  // [4096][3072] bf16
    unsigned short* attnb = qkvb  + (size_t)BS_ * 3 * D_;           // partial 0 / final
    unsigned short* xb    = attnb + (size_t)BS_ * D_;               // x, then partial 1
    unsigned short* wat   = xb    + (size_t)BS_ * D_;               // w_attn^T, then ml
    unsigned short* wpt   = wat   + (size_t)3 * D_ * D_;            // [1024][1024] bf16
    float2*         mlbuf = (float2*)wat;                           // 1 MB, overlays wat

    // 0) fused prep: x->bf16 + both weight transposes, one launch
    prep_fused<<<3072, 256, 0, stream>>>(x, xb, w_attn, wat, w_proj, wpt);

    // 1) QKV projection (bf16 MFMA, BN=128, XCD-swizzled) -> bf16 qkv
    //    Q columns (n < 1024) pre-scaled by 1/8 (exact in bf16).
    gemm_bt_bf16<unsigned short, 128><<<dim3(3 * D_ / 128, BS_ / 128), 256, 0, stream>>>(
        xb, wat, b_attn, qkvb, BS_, 3 * D_, D_, D_);

    // 2) split-K flash pass 1 (grid 1024 = 4 blocks/CU at VGPR<=64)
    flash_attn_split<<<dim3(S_ / 128, H_, B_ * 2), 512, 0, stream>>>(
        qkvb, amask, attnb, xb, mlbuf);

    // 3) combine halves in-place into attnb
    combine_halves<<<(BS_ * D_ / 8) / 256, 256, 0, stream>>>(attnb, xb, mlbuf);

    // 4) output projection (bf16 MFMA, BN=64, XCD-swizzled) -> fp32
    gemm_bt_bf16<float, 64><<<dim3(D_ / 64, BS_ / 128), 256, 0, stream>>>(
        attnb, wpt, b_proj, out, BS_, D_, D_, 0);
}

// Round 26
// 175.663 us; speedup vs baseline: 1.5585x; 1.5569x over previous
//
#include <hip/hip_runtime.h>
#include <math.h>

#define B_  2
#define S_  2048
#define D_  1024
#define H_  16
#define HD_ 64
#define BS_ (B_ * S_)          // 4096 token rows
#define SH_ (S_ / 2)           // split-K half length (1024 keys)

typedef float f32x4 __attribute__((ext_vector_type(4)));
typedef int   i32x4 __attribute__((ext_vector_type(4)));

__device__ __forceinline__ float bf2f(unsigned short u) {
    union { unsigned int i; float f; } c; c.i = ((unsigned int)u) << 16; return c.f;
}
__device__ __forceinline__ unsigned short f2bf(float f) {
    union { float f; unsigned int i; } c; c.f = f;
    unsigned int r = c.i + 0x7FFFu + ((c.i >> 16) & 1u);
    return (unsigned short)(r >> 16);
}
__device__ __forceinline__ unsigned int cvtpk_bf16(float lo, float hi) {
    unsigned int r;
    asm volatile("v_cvt_pk_bf16_f32 %0, %1, %2" : "=v"(r) : "v"(lo), "v"(hi));
    return r;
}
__device__ __forceinline__ void gl_lds16(const void* g, void* l) {
    __builtin_amdgcn_global_load_lds((const __attribute__((address_space(1))) void*)g,
                                     (__attribute__((address_space(3))) void*)l, 16, 0, 0);
}
__device__ __forceinline__ void mfma_bf16(f32x4& d, i32x4 a, i32x4 b) {
    asm volatile("v_mfma_f32_16x16x32_bf16 %0, %1, %2, %0" : "+v"(d) : "v"(a), "v"(b));
}

// ---------------------------------------------------------------------------
// Fused prep (single launch, r23-verified): block-range dispatch.
// ---------------------------------------------------------------------------
__device__ __forceinline__ void transpose_tile64(
    const float* __restrict__ W, unsigned short* __restrict__ Wt,
    int K, int N, int bx, int by, float (*t)[65])
{
    const int n0 = bx * 64, k0 = by * 64;
    const int tx = threadIdx.x & 63, ty = threadIdx.x >> 6;   // ty 0..3
#pragma unroll
    for (int kk = 0; kk < 64; kk += 4)
        t[kk + ty][tx] = W[(size_t)(k0 + kk + ty) * N + n0 + tx];
    __syncthreads();
    const int nrow = threadIdx.x >> 2;       // 0..63
    const int kq   = (threadIdx.x & 3) * 4;  // 0,4,8,12
#pragma unroll
    for (int p = 0; p < 4; ++p) {
        const int k = p * 16 + kq;
        ushort4 v = make_ushort4(f2bf(t[k + 0][nrow]), f2bf(t[k + 1][nrow]),
                                 f2bf(t[k + 2][nrow]), f2bf(t[k + 3][nrow]));
        *reinterpret_cast<ushort4*>(Wt + (size_t)(n0 + nrow) * K + k0 + k) = v;
    }
}

__global__ __launch_bounds__(256) void prep_fused(
    const float* __restrict__ x,      unsigned short* __restrict__ xb,
    const float* __restrict__ w_attn, unsigned short* __restrict__ wat,
    const float* __restrict__ w_proj, unsigned short* __restrict__ wpt)
{
    __shared__ float t[64][65];
    const int bid = blockIdx.x;
    if (bid < 2048) {
        const int i = (bid * 256 + threadIdx.x) * 8;
        const float4 a = *reinterpret_cast<const float4*>(x + i);
        const float4 b = *reinterpret_cast<const float4*>(x + i + 4);
        ushort4 u0 = make_ushort4(f2bf(a.x), f2bf(a.y), f2bf(a.z), f2bf(a.w));
        ushort4 u1 = make_ushort4(f2bf(b.x), f2bf(b.y), f2bf(b.z), f2bf(b.w));
        *reinterpret_cast<ushort4*>(xb + i)     = u0;
        *reinterpret_cast<ushort4*>(xb + i + 4) = u1;
    } else if (bid < 2816) {
        const int tb = bid - 2048;                 // 0..767: 48 x 16
        transpose_tile64(w_attn, wat, D_, 3 * D_, tb % 48, tb / 48, t);
    } else {
        const int tb = bid - 2816;                 // 0..255: 16 x 16
        transpose_tile64(w_proj, wpt, D_, D_, tb & 15, tb >> 4, t);
    }
}

// ---------------------------------------------------------------------------
// GEMM: C[M,N] = (A[M,K]_bf16 * Bt[N,K]_bf16^T + bias) * sc(n)   (r8/r12-
// verified core; r21 score-scale fold; r22 XCD-chunked block swizzle).
// ---------------------------------------------------------------------------
template <typename OutT, int BN>
__global__ __launch_bounds__(256) void gemm_bt_bf16(
    const unsigned short* __restrict__ A,   // [M][K]
    const unsigned short* __restrict__ Bt,  // [N][K]
    const float* __restrict__ bias,         // [N]
    OutT* __restrict__ C, int M, int N, int K, int qcols)
{
    constexpr int NW = BN / 2;    // wave n-extent
    constexpr int NI = NW / 16;   // n-frags per wave
    __shared__ alignas(16) unsigned short As[2][4096];
    __shared__ alignas(16) unsigned short Bs[2][BN * 32];

    const int tid  = threadIdx.x;
    const int wave = tid >> 6;
    const int l    = tid & 63;
    const int g    = l >> 4;
    const int r    = l & 15;
    const int wr   = wave >> 1, wc = wave & 1;

    // XCD-chunked swizzle (T1, m157): bijective, nwg % 8 == 0.
    const int nwg  = gridDim.x * gridDim.y;
    const int flat = blockIdx.x + gridDim.x * blockIdx.y;
    const int cpx  = nwg >> 3;
    const int swz  = (flat & 7) * cpx + (flat >> 3);
    const int bx   = swz % gridDim.x;
    const int by   = swz / gridDim.x;

    const int row0 = by * 128;
    const int col0 = bx * BN;
    const float sc = (col0 < qcols) ? 0.125f : 1.0f;   // block-uniform

    const size_t aoff0 = (size_t)(row0 +   0 + l) * K + wave * 8;
    const size_t aoff1 = (size_t)(row0 +  64 + l) * K + wave * 8;
    const size_t boff0 = (size_t)(col0 +   0 + l) * K + wave * 8;
    const size_t boff1 = (size_t)(col0 +  64 + l) * K + wave * 8;  // BN=128 only

    auto stage = [&](int kt, int buf) {
        gl_lds16(A + aoff0 + kt, &As[buf][wave * 1024]);
        gl_lds16(A + aoff1 + kt, &As[buf][wave * 1024 + 512]);
        if constexpr (BN == 128) {
            gl_lds16(Bt + boff0 + kt, &Bs[buf][wave * 1024]);
            gl_lds16(Bt + boff1 + kt, &Bs[buf][wave * 1024 + 512]);
        } else {
            gl_lds16(Bt + boff0 + kt, &Bs[buf][wave * 512]);
        }
    };

    f32x4 acc[4][NI];
#pragma unroll
    for (int mi = 0; mi < 4; ++mi)
#pragma unroll
        for (int ni = 0; ni < NI; ++ni) acc[mi][ni] = (f32x4)0.f;

    stage(0, 0);
    __syncthreads();

    for (int kt = 0; kt < K; kt += 32) {
        const int cur = (kt >> 5) & 1;
        if (kt + 32 < K) stage(kt + 32, cur ^ 1);

        const unsigned short* Ab = &As[cur][g * 1024];
        const unsigned short* Bb = &Bs[cur][g * (BN * 8)];
        i32x4 af[4], bf[NI];
#pragma unroll
        for (int mi = 0; mi < 4; ++mi)
            af[mi] = *reinterpret_cast<const i32x4*>(Ab + (wr * 64 + mi * 16 + r) * 8);
#pragma unroll
        for (int ni = 0; ni < NI; ++ni)
            bf[ni] = *reinterpret_cast<const i32x4*>(Bb + (wc * NW + ni * 16 + r) * 8);
#pragma unroll
        for (int mi = 0; mi < 4; ++mi)
#pragma unroll
            for (int ni = 0; ni < NI; ++ni)
                mfma_bf16(acc[mi][ni], af[mi], bf[ni]);

        __syncthreads();   // drains gl_lds (vmcnt) + ds reads; next buf ready
    }

#pragma unroll
    for (int ni = 0; ni < NI; ++ni) {
        const int n = col0 + wc * NW + ni * 16 + r;
        const float bv = bias[n];
#pragma unroll
        for (int mi = 0; mi < 4; ++mi) {
#pragma unroll
            for (int e = 0; e < 4; ++e) {
                const int m = row0 + wr * 64 + mi * 16 + g * 4 + e;
                const float val = (acc[mi][ni][e] + bv) * sc;
                if constexpr (sizeof(OutT) == 2)
                    C[(size_t)m * N + n] = (OutT)f2bf(val);
                else
                    C[(size_t)m * N + n] = (OutT)val;
            }
        }
    }
}

// ---------------------------------------------------------------------------
// Split-K MFMA flash attention, pass 1. r24 kernel MINUS the min-waves pin:
// r24's __launch_bounds__(512, 8) forced VGPR 60->32 and spilled (FETCH
// 410 MB, MfmaUtil 7%). Natural allocation is ~60 VGPR (r20/r23) — under
// the m69 64-boundary — so grid 1024 = 4 blocks/CU can reach 8 waves/SIMD
// without spilling. r11's null was at VGPR=64 (boundary, no TLP gain).
// ---------------------------------------------------------------------------
__global__ __launch_bounds__(512) void flash_attn_split(
    const unsigned short* __restrict__ qkv,  // [BS][3072], Q cols pre-scaled
    const float* __restrict__ mask,          // [B][S]
    unsigned short* __restrict__ op0,        // [BS][1024] partial half 0
    unsigned short* __restrict__ op1,        // [BS][1024] partial half 1
    float2* __restrict__ ml)                 // [2][B][H][S] (m, l)
{
    __shared__ alignas(16) unsigned short Klds[2][4096];  // [key][d^((key&7)<<3)]
    __shared__ alignas(16) unsigned short Vt[2][4096];    // [d][key^((d&7)<<3)]

    const int tid  = threadIdx.x;
    const int wave = tid >> 6;          // 0..7
    const int l    = tid & 63;
    const int g    = l >> 4;
    const int r    = l & 15;

    // XCD-chunked swizzle: 1024 blocks, chunk = 128 per XCD = 8 heads of one
    // (b,half) -> K/V footprint 2 MB per L2. Bijective.
    const int flat = blockIdx.x + 16 * blockIdx.y + 256 * blockIdx.z;
    const int swz  = (flat & 7) * 128 + (flat >> 3);
    const int zz   = swz >> 8;          // 0..3 = b*2 + half
    const int b    = zz >> 1;
    const int half = zz & 1;
    const int kv0  = half * SH_;
    const int h    = (swz >> 4) & 15;
    const int q0   = (swz & 15) * 128;
    const int qw   = q0 + wave * 16;    // this wave's 16 q-rows

    const size_t rs = 3 * (size_t)D_;
    const unsigned short* qb = qkv + (size_t)b * S_ * rs + (size_t)h * HD_;
    const unsigned short* kb = qb + D_;
    const unsigned short* vb = qb + 2 * D_;
    const float* mrow = mask + (size_t)b * S_;

    // Q fragments: q = qw + r, d = ks*32 + g*8 + j
    i32x4 qf[2];
#pragma unroll
    for (int ks = 0; ks < 2; ++ks)
        qf[ks] = *reinterpret_cast<const i32x4*>(
            qb + (size_t)(qw + r) * rs + ks * 32 + g * 8);

    // K staging (waves 0-3, r4 mapping): keys kt + wave*16 + t*8 + (l>>3)
    const int kkey = (wave & 3) * 16 + (l >> 3);
    const int kuni = ((l & 7) ^ (l >> 3)) * 8;
    // V staging (waves 4-7, r4 mapping with w' = wave-4)
    const int vkey = (wave & 3) * 16 + (l >> 2);
    const int vpart = l & 3;

    ushort4 vr[4];   // in-flight V registers (next tile's data)
    auto vload = [&](int kt) {
#pragma unroll
        for (int p = 0; p < 4; ++p)
            vr[p] = *reinterpret_cast<const ushort4*>(
                vb + (size_t)(kt + vkey) * rs + p * 16 + vpart * 4);
    };
    auto vwrite = [&](int buf) {
#pragma unroll
        for (int p = 0; p < 4; ++p) {
            const int d0 = p * 16 + vpart * 4;
            Vt[buf][(d0 + 0) * 64 + (vkey ^ (((d0 + 0) & 7) << 3))] = vr[p].x;
            Vt[buf][(d0 + 1) * 64 + (vkey ^ (((d0 + 1) & 7) << 3))] = vr[p].y;
            Vt[buf][(d0 + 2) * 64 + (vkey ^ (((d0 + 2) & 7) << 3))] = vr[p].z;
            Vt[buf][(d0 + 3) * 64 + (vkey ^ (((d0 + 3) & 7) << 3))] = vr[p].w;
        }
    };

    f32x4 acc[4];     // O^T: d = mi*16 + g*4 + e, q = r
    float m_i = -1e30f, l_i = 0.f;
#pragma unroll
    for (int mi = 0; mi < 4; ++mi) acc[mi] = (f32x4)0.f;

    // prologue: tile kv0 into buf 0; V regs for tile kv0+64 in flight
    if (wave < 4) {
        gl_lds16(kb + (size_t)(kv0 + kkey) * rs + kuni,     &Klds[0][(wave & 3) * 1024]);
        gl_lds16(kb + (size_t)(kv0 + kkey + 8) * rs + kuni, &Klds[0][(wave & 3) * 1024 + 512]);
    } else {
        vload(kv0);
        vwrite(0);        // waits vmcnt internally (prologue only)
        vload(kv0 + 64);  // next tile regs, drains at first barrier
    }
    __syncthreads();

    for (int kt = kv0; kt < kv0 + SH_; kt += 64) {
        const int cur = ((kt - kv0) >> 6) & 1;
        if (wave < 4) {
            if (kt + 64 < kv0 + SH_) {
                gl_lds16(kb + (size_t)(kt + 64 + kkey) * rs + kuni,
                         &Klds[cur ^ 1][(wave & 3) * 1024]);
                gl_lds16(kb + (size_t)(kt + 64 + kkey + 8) * rs + kuni,
                         &Klds[cur ^ 1][(wave & 3) * 1024 + 512]);
            }
        } else {
            if (kt + 64 < kv0 + SH_) vwrite(cur ^ 1);   // tile t+1 (drained)
            if (kt + 128 < kv0 + SH_) vload(kt + 128);  // issue t+2
        }

        const unsigned short* Kb = Klds[cur];
        const unsigned short* Vb = Vt[cur];

        // --- S^T = (Q/8)·K^T + mask : C-in = mask (key = S^T row) ---
        f32x4 s[4];
#pragma unroll
        for (int mi = 0; mi < 4; ++mi) {
            const float4 mk = *reinterpret_cast<const float4*>(
                mrow + kt + mi * 16 + g * 4);
            s[mi][0] = mk.x; s[mi][1] = mk.y; s[mi][2] = mk.z; s[mi][3] = mk.w;
        }
#pragma unroll
        for (int ks = 0; ks < 2; ++ks)
#pragma unroll
            for (int mi = 0; mi < 4; ++mi) {
                const i32x4 kf = *reinterpret_cast<const i32x4*>(
                    Kb + (mi * 16 + r) * 64 + ((ks * 32 + g * 8) ^ ((r & 7) << 3)));
                mfma_bf16(s[mi], kf, qf[ks]);
            }

        // --- online softmax + pack P to bf16 ---
        float tmax = -1e30f;
#pragma unroll
        for (int mi = 0; mi < 4; ++mi)
#pragma unroll
            for (int e = 0; e < 4; ++e)
                tmax = fmaxf(tmax, s[mi][e]);
        tmax = fmaxf(tmax, __shfl_xor(tmax, 16));
        tmax = fmaxf(tmax, __shfl_xor(tmax, 32));
        const float mnew = fmaxf(m_i, tmax);
        const float corr = __expf(m_i - mnew);
        m_i = mnew;

        unsigned int pk[4][2];   // [mi][wl]: keys (mi*16 + g*4 + 2wl, +1)
        float ls = 0.f;
#pragma unroll
        for (int mi = 0; mi < 4; ++mi) {
            const float p0 = __expf(s[mi][0] - mnew);
            const float p1 = __expf(s[mi][1] - mnew);
            const float p2 = __expf(s[mi][2] - mnew);
            const float p3 = __expf(s[mi][3] - mnew);
            ls += (p0 + p1) + (p2 + p3);
            pk[mi][0] = cvtpk_bf16(p0, p1);
            pk[mi][1] = cvtpk_bf16(p2, p3);
        }
        l_i = l_i * corr + ls;   // lane-partial over g; reduced at end
#pragma unroll
        for (int mi = 0; mi < 4; ++mi) acc[mi] *= corr;

        // --- PV: O^T += V^T · P^T ---
#pragma unroll
        for (int ks = 0; ks < 2; ++ks) {
            i32x4 pf;   // word w = keys ks*32 + g*8 + 2w, +1 of q-row r
#pragma unroll
            for (int w = 0; w < 4; ++w) {
                const int src = (((g & 1) * 2 + (w >> 1)) << 4) + r;
                const unsigned int vA = __shfl(pk[2 * ks + 0][w & 1], src);
                const unsigned int vB = __shfl(pk[2 * ks + 1][w & 1], src);
                pf[w] = (int)((g >> 1) ? vB : vA);
            }
#pragma unroll
            for (int mi = 0; mi < 4; ++mi) {
                const i32x4 vf = *reinterpret_cast<const i32x4*>(
                    Vb + (mi * 16 + r) * 64 + ((ks * 32 + g * 8) ^ ((r & 7) << 3)));
                mfma_bf16(acc[mi], vf, pf);
            }
        }

        __syncthreads();   // drains stage's vmcnt/lgkm; next buf ready
    }

    // --- epilogue: reduce l over g-lanes, write normalized partial + (m,l) ---
    float lf = l_i;
    lf += __shfl_xor(lf, 16);
    lf += __shfl_xor(lf, 32);
    const float inv = 1.0f / lf;
    const size_t token = (size_t)b * S_ + qw + r;
    unsigned short* obase = half ? op1 : op0;
#pragma unroll
    for (int mi = 0; mi < 4; ++mi) {
        const f32x4 v = acc[mi] * inv;
        uint2 w;
        w.x = cvtpk_bf16(v[0], v[1]);
        w.y = cvtpk_bf16(v[2], v[3]);
        *reinterpret_cast<uint2*>(
            obase + token * D_ + h * HD_ + mi * 16 + g * 4) = w;
    }
    if (l < 16) {   // g==0 lane per q-row
        const size_t mli = (((size_t)half * B_ + b) * H_ + h) * S_ + qw + l;
        ml[mli] = make_float2(m_i, lf);
    }
}

// ---------------------------------------------------------------------------
// Split-K combine (r11-verified): out = (w0*O0 + w1*O1)/(w0+w1),
// w_h = l_h * exp(m_h - M). In-place on o0.
// ---------------------------------------------------------------------------
__global__ __launch_bounds__(256) void combine_halves(
    unsigned short* o0,                       // [BS][1024] in/out (half 0)
    const unsigned short* __restrict__ o1,    // [BS][1024] (half 1)
    const float2* __restrict__ ml)            // [2][B][H][S]
{
    const int gid   = blockIdx.x * 256 + threadIdx.x;   // 0 .. 524287
    const int chunk = gid & 127;                         // 8-elem chunk in row
    const int token = gid >> 7;                          // 0..4095
    const int h     = chunk >> 3;
    const int b     = token >> 11;
    const int q     = token & 2047;

    const size_t mli = (((size_t)b) * H_ + h) * S_ + q;
    const float2 a0 = ml[mli];
    const float2 a1 = ml[(size_t)B_ * H_ * S_ + mli];
    const float M  = fmaxf(a0.x, a1.x);
    float w0 = a0.y * __expf(a0.x - M);
    float w1 = a1.y * __expf(a1.x - M);
    const float inv = 1.0f / (w0 + w1);
    w0 *= inv; w1 *= inv;

    const size_t off = (size_t)token * D_ + chunk * 8;
    const ushort4 x0 = *reinterpret_cast<const ushort4*>(o0 + off);
    const ushort4 x1 = *reinterpret_cast<const ushort4*>(o0 + off + 4);
    const ushort4 y0 = *reinterpret_cast<const ushort4*>(o1 + off);
    const ushort4 y1 = *reinterpret_cast<const ushort4*>(o1 + off + 4);
    ushort4 r0, r1;
    r0.x = f2bf(w0 * bf2f(x0.x) + w1 * bf2f(y0.x));
    r0.y = f2bf(w0 * bf2f(x0.y) + w1 * bf2f(y0.y));
    r0.z = f2bf(w0 * bf2f(x0.z) + w1 * bf2f(y0.z));
    r0.w = f2bf(w0 * bf2f(x0.w) + w1 * bf2f(y0.w));
    r1.x = f2bf(w0 * bf2f(x1.x) + w1 * bf2f(y1.x));
    r1.y = f2bf(w0 * bf2f(x1.y) + w1 * bf2f(y1.y));
    r1.z = f2bf(w0 * bf2f(x1.z) + w1 * bf2f(y1.z));
    r1.w = f2bf(w0 * bf2f(x1.w) + w1 * bf2f(y1.w));
    *reinterpret_cast<ushort4*>(o0 + off)     = r0;
    *reinterpret_cast<ushort4*>(o0 + off + 4) = r1;
}

// ---------------------------------------------------------------------------
extern "C" void kernel_launch(void* const* d_in, const int* in_sizes, int n_in,
                              void* d_out, int out_size, void* d_ws, size_t ws_size,
                              hipStream_t stream)
{
    const float* x      = (const float*)d_in[0];   // [2,2048,1024]
    const float* amask  = (const float*)d_in[1];   // [2,2048]
    const float* w_attn = (const float*)d_in[2];   // [1024,3072]
    const float* b_attn = (const float*)d_in[3];   // [3072]
    const float* w_proj = (const float*)d_in[4];   // [1024,1024]
    const float* b_proj = (const float*)d_in[5];   // [1024]
    float* out = (float*)d_out;                    // [2,2048,1024] fp32

    unsigned short* qkvb  = (unsigned short*)d_ws;                  // [4096][3072] bf16
    unsigned short* attnb = qkvb  + (size_t)BS_ * 3 * D_;           // partial 0 / final
    unsigned short* xb    = attnb + (size_t)BS_ * D_;               // x, then partial 1
    unsigned short* wat   = xb    + (size_t)BS_ * D_;               // w_attn^T, then ml
    unsigned short* wpt   = wat   + (size_t)3 * D_ * D_;            // [1024][1024] bf16
    float2*         mlbuf = (float2*)wat;                           // 1 MB, overlays wat

    // 0) fused prep: x->bf16 + both weight transposes, one launch
    prep_fused<<<3072, 256, 0, stream>>>(x, xb, w_attn, wat, w_proj, wpt);

    // 1) QKV projection (bf16 MFMA, BN=128, XCD-swizzled) -> bf16 qkv
    //    Q columns (n < 1024) pre-scaled by 1/8 (exact in bf16).
    gemm_bt_bf16<unsigned short, 128><<<dim3(3 * D_ / 128, BS_ / 128), 256, 0, stream>>>(
        xb, wat, b_attn, qkvb, BS_, 3 * D_, D_, D_);

    // 2) split-K flash pass 1 (grid 1024; natural VGPR ~60 < 64 boundary)
    flash_attn_split<<<dim3(S_ / 128, H_, B_ * 2), 512, 0, stream>>>(
        qkvb, amask, attnb, xb, mlbuf);

    // 3) combine halves in-place into attnb
    combine_halves<<<(BS_ * D_ / 8) / 256, 256, 0, stream>>>(attnb, xb, mlbuf);

    // 4) output projection (bf16 MFMA, BN=64, XCD-swizzled) -> fp32
    gemm_bt_bf16<float, 64><<<dim3(D_ / 64, BS_ / 128), 256, 0, stream>>>(
        attnb, wpt, b_proj, out, BS_, D_, D_, 0);
}

// Round 27
// 167.245 us; speedup vs baseline: 1.6369x; 1.0503x over previous
//
#include <hip/hip_runtime.h>
#include <math.h>

#define B_  2
#define S_  2048
#define D_  1024
#define H_  16
#define HD_ 64
#define BS_ (B_ * S_)          // 4096 token rows

typedef float f32x4 __attribute__((ext_vector_type(4)));
typedef int   i32x4 __attribute__((ext_vector_type(4)));

__device__ __forceinline__ float bf2f(unsigned short u) {
    union { unsigned int i; float f; } c; c.i = ((unsigned int)u) << 16; return c.f;
}
__device__ __forceinline__ unsigned short f2bf(float f) {
    union { float f; unsigned int i; } c; c.f = f;
    unsigned int r = c.i + 0x7FFFu + ((c.i >> 16) & 1u);
    return (unsigned short)(r >> 16);
}
__device__ __forceinline__ unsigned int cvtpk_bf16(float lo, float hi) {
    unsigned int r;
    asm volatile("v_cvt_pk_bf16_f32 %0, %1, %2" : "=v"(r) : "v"(lo), "v"(hi));
    return r;
}
__device__ __forceinline__ void gl_lds16(const void* g, void* l) {
    __builtin_amdgcn_global_load_lds((const __attribute__((address_space(1))) void*)g,
                                     (__attribute__((address_space(3))) void*)l, 16, 0, 0);
}
__device__ __forceinline__ void mfma_bf16(f32x4& d, i32x4 a, i32x4 b) {
    asm volatile("v_mfma_f32_16x16x32_bf16 %0, %1, %2, %0" : "+v"(d) : "v"(a), "v"(b));
}

// ---------------------------------------------------------------------------
// Fused prep (single launch, r23-verified): block-range dispatch.
//   blocks [0, 2048)      : x fp32 -> bf16 (8 elems/thread)
//   blocks [2048, 2816)   : w_attn [1024][3072] -> wat [3072][1024] bf16
//   blocks [2816, 3072)   : w_proj [1024][1024] -> wpt [1024][1024] bf16
// ---------------------------------------------------------------------------
__device__ __forceinline__ void transpose_tile64(
    const float* __restrict__ W, unsigned short* __restrict__ Wt,
    int K, int N, int bx, int by, float (*t)[65])
{
    const int n0 = bx * 64, k0 = by * 64;
    const int tx = threadIdx.x & 63, ty = threadIdx.x >> 6;   // ty 0..3
#pragma unroll
    for (int kk = 0; kk < 64; kk += 4)
        t[kk + ty][tx] = W[(size_t)(k0 + kk + ty) * N + n0 + tx];
    __syncthreads();
    const int nrow = threadIdx.x >> 2;       // 0..63
    const int kq   = (threadIdx.x & 3) * 4;  // 0,4,8,12
#pragma unroll
    for (int p = 0; p < 4; ++p) {
        const int k = p * 16 + kq;
        ushort4 v = make_ushort4(f2bf(t[k + 0][nrow]), f2bf(t[k + 1][nrow]),
                                 f2bf(t[k + 2][nrow]), f2bf(t[k + 3][nrow]));
        *reinterpret_cast<ushort4*>(Wt + (size_t)(n0 + nrow) * K + k0 + k) = v;
    }
}

__global__ __launch_bounds__(256) void prep_fused(
    const float* __restrict__ x,      unsigned short* __restrict__ xb,
    const float* __restrict__ w_attn, unsigned short* __restrict__ wat,
    const float* __restrict__ w_proj, unsigned short* __restrict__ wpt)
{
    __shared__ float t[64][65];
    const int bid = blockIdx.x;
    if (bid < 2048) {
        const int i = (bid * 256 + threadIdx.x) * 8;
        const float4 a = *reinterpret_cast<const float4*>(x + i);
        const float4 b = *reinterpret_cast<const float4*>(x + i + 4);
        ushort4 u0 = make_ushort4(f2bf(a.x), f2bf(a.y), f2bf(a.z), f2bf(a.w));
        ushort4 u1 = make_ushort4(f2bf(b.x), f2bf(b.y), f2bf(b.z), f2bf(b.w));
        *reinterpret_cast<ushort4*>(xb + i)     = u0;
        *reinterpret_cast<ushort4*>(xb + i + 4) = u1;
    } else if (bid < 2816) {
        const int tb = bid - 2048;                 // 0..767: 48 x 16
        transpose_tile64(w_attn, wat, D_, 3 * D_, tb % 48, tb / 48, t);
    } else {
        const int tb = bid - 2816;                 // 0..255: 16 x 16
        transpose_tile64(w_proj, wpt, D_, D_, tb & 15, tb >> 4, t);
    }
}

// ---------------------------------------------------------------------------
// GEMM: C[M,N] = (A[M,K]_bf16 * Bt[N,K]_bf16^T + bias) * sc(n)   (r8/r12-
// verified core; r21 score-scale fold; r22 XCD-chunked block swizzle).
// Tile choice is STARVATION-dependent (r18): BN=64 only when BN=128 leaves
// <2 blocks/CU (proj). QKV stays BN=128 (r18: BN=64 cost -22 µs).
// ---------------------------------------------------------------------------
template <typename OutT, int BN>
__global__ __launch_bounds__(256) void gemm_bt_bf16(
    const unsigned short* __restrict__ A,   // [M][K]
    const unsigned short* __restrict__ Bt,  // [N][K]
    const float* __restrict__ bias,         // [N]
    OutT* __restrict__ C, int M, int N, int K, int qcols)
{
    constexpr int NW = BN / 2;    // wave n-extent
    constexpr int NI = NW / 16;   // n-frags per wave
    __shared__ alignas(16) unsigned short As[2][4096];
    __shared__ alignas(16) unsigned short Bs[2][BN * 32];

    const int tid  = threadIdx.x;
    const int wave = tid >> 6;
    const int l    = tid & 63;
    const int g    = l >> 4;
    const int r    = l & 15;
    const int wr   = wave >> 1, wc = wave & 1;

    // XCD-chunked swizzle (T1, m157): bijective, nwg % 8 == 0.
    const int nwg  = gridDim.x * gridDim.y;
    const int flat = blockIdx.x + gridDim.x * blockIdx.y;
    const int cpx  = nwg >> 3;
    const int swz  = (flat & 7) * cpx + (flat >> 3);
    const int bx   = swz % gridDim.x;
    const int by   = swz / gridDim.x;

    const int row0 = by * 128;
    const int col0 = bx * BN;
    const float sc = (col0 < qcols) ? 0.125f : 1.0f;   // block-uniform

    const size_t aoff0 = (size_t)(row0 +   0 + l) * K + wave * 8;
    const size_t aoff1 = (size_t)(row0 +  64 + l) * K + wave * 8;
    const size_t boff0 = (size_t)(col0 +   0 + l) * K + wave * 8;
    const size_t boff1 = (size_t)(col0 +  64 + l) * K + wave * 8;  // BN=128 only

    auto stage = [&](int kt, int buf) {
        gl_lds16(A + aoff0 + kt, &As[buf][wave * 1024]);
        gl_lds16(A + aoff1 + kt, &As[buf][wave * 1024 + 512]);
        if constexpr (BN == 128) {
            gl_lds16(Bt + boff0 + kt, &Bs[buf][wave * 1024]);
            gl_lds16(Bt + boff1 + kt, &Bs[buf][wave * 1024 + 512]);
        } else {
            gl_lds16(Bt + boff0 + kt, &Bs[buf][wave * 512]);
        }
    };

    f32x4 acc[4][NI];
#pragma unroll
    for (int mi = 0; mi < 4; ++mi)
#pragma unroll
        for (int ni = 0; ni < NI; ++ni) acc[mi][ni] = (f32x4)0.f;

    stage(0, 0);
    __syncthreads();

    for (int kt = 0; kt < K; kt += 32) {
        const int cur = (kt >> 5) & 1;
        if (kt + 32 < K) stage(kt + 32, cur ^ 1);

        const unsigned short* Ab = &As[cur][g * 1024];
        const unsigned short* Bb = &Bs[cur][g * (BN * 8)];
        i32x4 af[4], bf[NI];
#pragma unroll
        for (int mi = 0; mi < 4; ++mi)
            af[mi] = *reinterpret_cast<const i32x4*>(Ab + (wr * 64 + mi * 16 + r) * 8);
#pragma unroll
        for (int ni = 0; ni < NI; ++ni)
            bf[ni] = *reinterpret_cast<const i32x4*>(Bb + (wc * NW + ni * 16 + r) * 8);
#pragma unroll
        for (int mi = 0; mi < 4; ++mi)
#pragma unroll
            for (int ni = 0; ni < NI; ++ni)
                mfma_bf16(acc[mi][ni], af[mi], bf[ni]);

        __syncthreads();   // drains gl_lds (vmcnt) + ds reads; next buf ready
    }

#pragma unroll
    for (int ni = 0; ni < NI; ++ni) {
        const int n = col0 + wc * NW + ni * 16 + r;
        const float bv = bias[n];
#pragma unroll
        for (int mi = 0; mi < 4; ++mi) {
#pragma unroll
            for (int e = 0; e < 4; ++e) {
                const int m = row0 + wr * 64 + mi * 16 + g * 4 + e;
                const float val = (acc[mi][ni][e] + bv) * sc;
                if constexpr (sizeof(OutT) == 2)
                    C[(size_t)m * N + n] = (OutT)f2bf(val);
                else
                    C[(size_t)m * N + n] = (OutT)val;
            }
        }
    }
}

// ---------------------------------------------------------------------------
// MFMA flash attention, 8 waves x 16 q-rows, Q tile 128, KV tile 64.
// r13-VERIFIED structure; r21 fold (pre-scaled Q, mask as S^T C-in);
// r22 XCD-chunked swizzle. FINAL FORM — structural ceiling analysis:
//   MFMA floor 13.4 µs; measured 87 µs = serial per-tile chain
//   (MFMA->softmax->repack->MFMA->barrier) x 32 tiles at the co-residency
//   cap. Cap is STRUCTURAL: r11 (VGPR=64), r24 (pinned, spilled), r26
//   (clean, VGPR=60, grid 1024) all failed to exceed ~2 blocks/CU for this
//   512-thread/32KB shape. Known-negative: balanced staging (r14),
//   exp2+defer-max (r10), setprio (r10), split-K (r11/r24/r26), KVBLK=128
//   (r9), BN=64 QKV (r18).
// ---------------------------------------------------------------------------
__global__ __launch_bounds__(512) void flash_attn_mfma(
    const unsigned short* __restrict__ qkv,  // [BS][3072], Q cols pre-scaled
    const float* __restrict__ mask,          // [B][S]
    unsigned short* __restrict__ out)        // [BS][1024]
{
    __shared__ alignas(16) unsigned short Klds[2][4096];  // [key][d^((key&7)<<3)]
    __shared__ alignas(16) unsigned short Vt[2][4096];    // [d][key^((d&7)<<3)]

    const int tid  = threadIdx.x;
    const int wave = tid >> 6;          // 0..7
    const int l    = tid & 63;
    const int g    = l >> 4;
    const int r    = l & 15;

    // XCD-chunked swizzle (T1): 64 logical blocks per XCD = 4 complete
    // (b,h) groups x 16 q-tiles. Bijective (512 blocks).
    const int flat = blockIdx.x + 16 * blockIdx.y + 256 * blockIdx.z;
    const int swz  = (flat & 7) * 64 + (flat >> 3);
    const int b    = swz >> 8;
    const int h    = (swz >> 4) & 15;
    const int q0   = (swz & 15) * 128;
    const int qw   = q0 + wave * 16;    // this wave's 16 q-rows

    const size_t rs = 3 * (size_t)D_;
    const unsigned short* qb = qkv + (size_t)b * S_ * rs + (size_t)h * HD_;
    const unsigned short* kb = qb + D_;
    const unsigned short* vb = qb + 2 * D_;
    const float* mrow = mask + (size_t)b * S_;

    // Q fragments: q = qw + r, d = ks*32 + g*8 + j
    i32x4 qf[2];
#pragma unroll
    for (int ks = 0; ks < 2; ++ks)
        qf[ks] = *reinterpret_cast<const i32x4*>(
            qb + (size_t)(qw + r) * rs + ks * 32 + g * 8);

    // K staging (waves 0-3, r4 mapping): keys wave*16 + t*8 + (l>>3)
    const int kkey = (wave & 3) * 16 + (l >> 3);
    const int kuni = ((l & 7) ^ (l >> 3)) * 8;
    // V staging (waves 4-7, r4 mapping with w' = wave-4)
    const int vkey = (wave & 3) * 16 + (l >> 2);
    const int vpart = l & 3;

    ushort4 vr[4];   // in-flight V registers (next tile's data)
    auto vload = [&](int kt) {
#pragma unroll
        for (int p = 0; p < 4; ++p)
            vr[p] = *reinterpret_cast<const ushort4*>(
                vb + (size_t)(kt + vkey) * rs + p * 16 + vpart * 4);
    };
    auto vwrite = [&](int buf) {
#pragma unroll
        for (int p = 0; p < 4; ++p) {
            const int d0 = p * 16 + vpart * 4;
            Vt[buf][(d0 + 0) * 64 + (vkey ^ (((d0 + 0) & 7) << 3))] = vr[p].x;
            Vt[buf][(d0 + 1) * 64 + (vkey ^ (((d0 + 1) & 7) << 3))] = vr[p].y;
            Vt[buf][(d0 + 2) * 64 + (vkey ^ (((d0 + 2) & 7) << 3))] = vr[p].z;
            Vt[buf][(d0 + 3) * 64 + (vkey ^ (((d0 + 3) & 7) << 3))] = vr[p].w;
        }
    };

    f32x4 acc[4];     // O^T: d = mi*16 + g*4 + e, q = r
    float m_i = -1e30f, l_i = 0.f;
#pragma unroll
    for (int mi = 0; mi < 4; ++mi) acc[mi] = (f32x4)0.f;

    // prologue: tile 0 into buf 0; V regs for tile 1 in flight
    if (wave < 4) {
        gl_lds16(kb + (size_t)(0 + kkey) * rs + kuni,     &Klds[0][(wave & 3) * 1024]);
        gl_lds16(kb + (size_t)(0 + kkey + 8) * rs + kuni, &Klds[0][(wave & 3) * 1024 + 512]);
    } else {
        vload(0);
        vwrite(0);        // waits vmcnt internally (prologue only)
        vload(64);        // tile 1 regs, drains at first barrier
    }
    __syncthreads();

    for (int kt = 0; kt < S_; kt += 64) {
        const int cur = (kt >> 6) & 1;
        if (wave < 4) {
            if (kt + 64 < S_) {
                gl_lds16(kb + (size_t)(kt + 64 + kkey) * rs + kuni,
                         &Klds[cur ^ 1][(wave & 3) * 1024]);
                gl_lds16(kb + (size_t)(kt + 64 + kkey + 8) * rs + kuni,
                         &Klds[cur ^ 1][(wave & 3) * 1024 + 512]);
            }
        } else {
            if (kt + 64 < S_) vwrite(cur ^ 1);   // vr = tile t+1 (loads drained)
            if (kt + 128 < S_) vload(kt + 128);  // issue t+2; hides under compute
        }

        const unsigned short* Kb = Klds[cur];
        const unsigned short* Vb = Vt[cur];

        // --- S^T = (Q/8)·K^T + mask : C-in = mask (key = S^T row) ---
        f32x4 s[4];
#pragma unroll
        for (int mi = 0; mi < 4; ++mi) {
            const float4 mk = *reinterpret_cast<const float4*>(
                mrow + kt + mi * 16 + g * 4);
            s[mi][0] = mk.x; s[mi][1] = mk.y; s[mi][2] = mk.z; s[mi][3] = mk.w;
        }
#pragma unroll
        for (int ks = 0; ks < 2; ++ks)
#pragma unroll
            for (int mi = 0; mi < 4; ++mi) {
                const i32x4 kf = *reinterpret_cast<const i32x4*>(
                    Kb + (mi * 16 + r) * 64 + ((ks * 32 + g * 8) ^ ((r & 7) << 3)));
                mfma_bf16(s[mi], kf, qf[ks]);
            }

        // --- online softmax + pack P to bf16 ---
        float tmax = -1e30f;
#pragma unroll
        for (int mi = 0; mi < 4; ++mi)
#pragma unroll
            for (int e = 0; e < 4; ++e)
                tmax = fmaxf(tmax, s[mi][e]);
        tmax = fmaxf(tmax, __shfl_xor(tmax, 16));
        tmax = fmaxf(tmax, __shfl_xor(tmax, 32));
        const float mnew = fmaxf(m_i, tmax);
        const float corr = __expf(m_i - mnew);
        m_i = mnew;

        unsigned int pk[4][2];   // [mi][wl]: keys (mi*16 + g*4 + 2wl, +1)
        float ls = 0.f;
#pragma unroll
        for (int mi = 0; mi < 4; ++mi) {
            const float p0 = __expf(s[mi][0] - mnew);
            const float p1 = __expf(s[mi][1] - mnew);
            const float p2 = __expf(s[mi][2] - mnew);
            const float p3 = __expf(s[mi][3] - mnew);
            ls += (p0 + p1) + (p2 + p3);
            pk[mi][0] = cvtpk_bf16(p0, p1);
            pk[mi][1] = cvtpk_bf16(p2, p3);
        }
        l_i = l_i * corr + ls;   // lane-partial over g; reduced at end
#pragma unroll
        for (int mi = 0; mi < 4; ++mi) acc[mi] *= corr;

        // --- PV: O^T += V^T · P^T ---
#pragma unroll
        for (int ks = 0; ks < 2; ++ks) {
            i32x4 pf;   // word w = keys ks*32 + g*8 + 2w, +1 of q-row r
#pragma unroll
            for (int w = 0; w < 4; ++w) {
                const int src = (((g & 1) * 2 + (w >> 1)) << 4) + r;
                const unsigned int vA = __shfl(pk[2 * ks + 0][w & 1], src);
                const unsigned int vB = __shfl(pk[2 * ks + 1][w & 1], src);
                pf[w] = (int)((g >> 1) ? vB : vA);
            }
#pragma unroll
            for (int mi = 0; mi < 4; ++mi) {
                const i32x4 vf = *reinterpret_cast<const i32x4*>(
                    Vb + (mi * 16 + r) * 64 + ((ks * 32 + g * 8) ^ ((r & 7) << 3)));
                mfma_bf16(acc[mi], vf, pf);
            }
        }

        __syncthreads();   // drains stage's vmcnt/lgkm; next buf ready
    }

    // --- epilogue: reduce l over g-lanes, divide, store bf16 ---
    float lf = l_i;
    lf += __shfl_xor(lf, 16);
    lf += __shfl_xor(lf, 32);
    const float inv = 1.0f / lf;
    const size_t token = (size_t)b * S_ + qw + r;
#pragma unroll
    for (int mi = 0; mi < 4; ++mi) {
        const f32x4 v = acc[mi] * inv;
        uint2 w;
        w.x = cvtpk_bf16(v[0], v[1]);
        w.y = cvtpk_bf16(v[2], v[3]);
        *reinterpret_cast<uint2*>(
            out + token * D_ + h * HD_ + mi * 16 + g * 4) = w;
    }
}

// ---------------------------------------------------------------------------
extern "C" void kernel_launch(void* const* d_in, const int* in_sizes, int n_in,
                              void* d_out, int out_size, void* d_ws, size_t ws_size,
                              hipStream_t stream)
{
    const float* x      = (const float*)d_in[0];   // [2,2048,1024]
    const float* amask  = (const float*)d_in[1];   // [2,2048]
    const float* w_attn = (const float*)d_in[2];   // [1024,3072]
    const float* b_attn = (const float*)d_in[3];   // [3072]
    const float* w_proj = (const float*)d_in[4];   // [1024,1024]
    const float* b_proj = (const float*)d_in[5];   // [1024]
    float* out = (float*)d_out;                    // [2,2048,1024] fp32

    unsigned short* qkvb  = (unsigned short*)d_ws;                  // [4096][3072] bf16
    unsigned short* attnb = qkvb  + (size_t)BS_ * 3 * D_;           // [4096][1024] bf16
    unsigned short* xb    = attnb + (size_t)BS_ * D_;               // [4096][1024] bf16
    unsigned short* wat   = xb    + (size_t)BS_ * D_;               // [3072][1024] bf16
    unsigned short* wpt   = wat   + (size_t)3 * D_ * D_;            // [1024][1024] bf16

    // 0) fused prep: x->bf16 + both weight transposes, one launch
    prep_fused<<<3072, 256, 0, stream>>>(x, xb, w_attn, wat, w_proj, wpt);

    // 1) QKV projection (bf16 MFMA, BN=128, XCD-swizzled) -> bf16 qkv
    //    Q columns (n < 1024) pre-scaled by 1/8 (exact in bf16).
    gemm_bt_bf16<unsigned short, 128><<<dim3(3 * D_ / 128, BS_ / 128), 256, 0, stream>>>(
        xb, wat, b_attn, qkvb, BS_, 3 * D_, D_, D_);

    // 2) MFMA flash attention (XCD-swizzled) -> bf16
    flash_attn_mfma<<<dim3(S_ / 128, H_, B_), 512, 0, stream>>>(qkvb, amask, attnb);

    // 3) output projection (bf16 MFMA, BN=64, XCD-swizzled) -> fp32
    gemm_bt_bf16<float, 64><<<dim3(D_ / 64, BS_ / 128), 256, 0, stream>>>(
        attnb, wpt, b_proj, out, BS_, D_, D_, 0);
}